// Round 21
// baseline (291.741 us; speedup 1.0000x reference)
//
#include <hip/hip_runtime.h>
#include <hip/hip_fp16.h>

// MultiHeadAttention: n=4096, e=128, H=8, fp32 in/out.
// [conv_weights] w_proj -> f16^T; w_qkv -> f16 permuted-transposed (Q pre-scaled
//                by log2(e))
// [qkv_gemm2]    f16 MFMA GEMM (f32 x converted in-kernel); V d-major direct,
//                Q/K n-major via LDS transpose
// [flash_attn]   KVBLK=64, split-K x4, grid 1024 = 4 blocks/CU (32KB LDS each).
//                Stagger maximized: co-residency lands ~75% of cap (R12/R20 data)
//                -> ~3 resident blocks. launch_bounds(256,4): cap 128 >= 84 used.
//                R20 lesson: barrier rate is NOT the lever (KVBLK=128 halved it
//                and regressed); independent-block stagger is.
// [proj_combine] 4-way combine (vectorized) + dt-split GEMM

#define N_TOK 4096
#define DH 128
#define NH 8

#define EXP2F(x) __builtin_amdgcn_exp2f(x)

typedef _Float16 f16;
typedef __attribute__((ext_vector_type(8))) _Float16 f16x8;
typedef __attribute__((ext_vector_type(2))) __fp16 hf2;
typedef __attribute__((ext_vector_type(4))) __fp16 hf4;
typedef __attribute__((ext_vector_type(4))) float f32x4;

#define GLD16(gsrc, ldst) __builtin_amdgcn_global_load_lds( \
    (const __attribute__((address_space(1))) void*)(gsrc), \
    (__attribute__((address_space(3))) void*)(ldst), 16, 0, 0)

// ---------------- conv: both weight matrices, one launch ------------------
__global__ __launch_bounds__(256) void conv_weights(
    const float* __restrict__ w_proj, const float* __restrict__ w_qkv,
    const float* __restrict__ b_qkv,
    f16* __restrict__ wpT, f16* __restrict__ wqkvT, float* __restrict__ bperm)
{
  int t = blockIdx.x * 256 + threadIdx.x;   // 0 .. 524287
  if (t < 131072) {
    int k = t >> 7, col = t & 127;
    wpT[col * 1024 + k] = (f16)w_proj[t];
  } else {
    t -= 131072;                            // 0 .. 393215 = 128 * 3072
    int k = t / 3072;
    int col = t - k * 3072;
    int hh = col / 384;
    int rem = col - hh * 384;
    int d = rem / 3;
    int s = rem - d * 3;
    int colp = s * 1024 + hh * 128 + d;
    float scale = (s == 0) ? 1.4426950408889634f : 1.0f;
    wqkvT[colp * 128 + k] = (f16)(w_qkv[t] * scale);
    if (k == 0) bperm[colp] = b_qkv[col] * scale;
  }
}

// ---------------- qkv GEMM v2: f16 MFMA (f32 x input) --------------------
__global__ __launch_bounds__(256) void qkv_gemm2(
    const float* __restrict__ x, const f16* __restrict__ wqkvT,
    const float* __restrict__ bperm,
    f16* __restrict__ Qh, f16* __restrict__ Kh, f16* __restrict__ Vt)
{
  const int cb = blockIdx.x;               // 0..23: s = cb>>3, h = cb&7
  const int rb = blockIdx.y;               // 0..31: rows rb*128
  const int tid = threadIdx.x;
  const int w = tid >> 6, lane = tid & 63;
  const int l16 = lane & 15, lhi = lane >> 4;
  const int s = cb >> 3, h = cb & 7;

  f16x8 xf[2][4];
#pragma unroll
  for (int m = 0; m < 2; ++m)
#pragma unroll
    for (int kt = 0; kt < 4; ++kt) {
      const float* xp = x + (size_t)(rb * 128 + w * 32 + m * 16 + l16) * 128 + kt * 32 + lhi * 8;
      f32x4 x0 = *(const f32x4*)xp, x1 = *(const f32x4*)(xp + 4);
      f16x8 v;
#pragma unroll
      for (int j = 0; j < 4; ++j) { v[j] = (f16)x0[j]; v[4 + j] = (f16)x1[j]; }
      xf[m][kt] = v;
    }

  f32x4 acc[8][2];
#pragma unroll
  for (int nt = 0; nt < 8; ++nt)
#pragma unroll
    for (int m = 0; m < 2; ++m) acc[nt][m] = (f32x4){0.f, 0.f, 0.f, 0.f};

#pragma unroll
  for (int nt = 0; nt < 8; ++nt)
#pragma unroll
    for (int kt = 0; kt < 4; ++kt) {
      f16x8 wf = *(const f16x8*)(wqkvT + (size_t)(cb * 128 + nt * 16 + l16) * 128 + kt * 32 + lhi * 8);
      acc[nt][0] = __builtin_amdgcn_mfma_f32_16x16x32_f16(wf, xf[0][kt], acc[nt][0], 0, 0, 0);
      acc[nt][1] = __builtin_amdgcn_mfma_f32_16x16x32_f16(wf, xf[1][kt], acc[nt][1], 0, 0, 0);
    }

#pragma unroll
  for (int nt = 0; nt < 8; ++nt) {
    f32x4 bb = *(const f32x4*)(bperm + cb * 128 + nt * 16 + 4 * lhi);
#pragma unroll
    for (int m = 0; m < 2; ++m) acc[nt][m] += bb;
  }

  if (s == 2) {            // V: direct d-major store [h*128+d][n]
#pragma unroll
    for (int nt = 0; nt < 8; ++nt)
#pragma unroll
      for (int m = 0; m < 2; ++m)
#pragma unroll
        for (int r = 0; r < 4; ++r)
          Vt[(size_t)(h * 128 + nt * 16 + 4 * lhi + r) * N_TOK + rb * 128 + w * 32 + m * 16 + l16] =
              (f16)acc[nt][m][r];
  } else {                 // Q/K: LDS transpose -> n-major [n][d]
    __shared__ f16 tr[128][136];
#pragma unroll
    for (int nt = 0; nt < 8; ++nt)
#pragma unroll
      for (int m = 0; m < 2; ++m)
#pragma unroll
        for (int r = 0; r < 4; ++r)
          tr[w * 32 + m * 16 + l16][nt * 16 + 4 * lhi + r] = (f16)acc[nt][m][r];
    __syncthreads();
    f16* dst = (s == 0 ? Qh : Kh) + (size_t)(h * N_TOK + rb * 128) * 128;
    int r = tid >> 1, dh = (tid & 1) * 64;
#pragma unroll
    for (int i = 0; i < 8; ++i)
      *(f16x8*)(dst + r * 128 + dh + i * 8) = *(const f16x8*)(&tr[r][dh + i * 8]);
  }
}

// ---------------- flash attention: 4 waves, split-K x4, 32 KB LDS --------
// grid 1024: h = bid&7 (XCD pin), sp = (bid>>3)&3, qb = bid>>5 (0..31).
// Block covers 128 q-rows; single-buffered K (16K) + V (16K); 4 blocks/CU.
__global__ __launch_bounds__(256, 4) void flash_attn(
    const f16* __restrict__ Qh, const f16* __restrict__ Kh,
    const f16* __restrict__ Vt, f16* __restrict__ opart, float* __restrict__ mlpart)
{
  const int bid = blockIdx.x;
  const int h = bid & 7;
  const int sp = (bid >> 3) & 3;
  const int qb = bid >> 5;
  const int tid = threadIdx.x;
  const int w = tid >> 6, lane = tid & 63;
  const int l16 = lane & 15, lhi = lane >> 4;

  __shared__ __align__(16) char smem[32768];   // K @0 (16K), V @16K

  f16x8 qf[2][4];
#pragma unroll
  for (int m = 0; m < 2; ++m)
#pragma unroll
    for (int kt = 0; kt < 4; ++kt)
      qf[m][kt] = *(const f16x8*)(Qh +
          (size_t)(h * N_TOK + qb * 128 + w * 32 + m * 16 + l16) * DH + kt * 32 + lhi * 8);

  // K A-row permutation pi = 32*(nt>>1) + 8*(i>>2) + 4*(nt&1) + (i&3); XOR swizzle
  int koff[4][4], voff[2][8];
#pragma unroll
  for (int nt = 0; nt < 4; ++nt) {
    int row = 32 * (nt >> 1) + 8 * (l16 >> 2) + 4 * (nt & 1) + (l16 & 3);
    int fk = (row & 3) | ((row & 8) >> 1);
#pragma unroll
    for (int kt = 0; kt < 4; ++kt)
      koff[nt][kt] = row * 256 + ((kt * 4 + lhi) ^ fk) * 16;
  }
#pragma unroll
  for (int ks = 0; ks < 2; ++ks)
#pragma unroll
    for (int dt = 0; dt < 8; ++dt) {
      int rowv = dt * 16 + l16;
      voff[ks][dt] = rowv * 128 + (((ks * 4 + lhi) ^ (rowv & 7))) * 16;
    }

  f32x4 o[2][8];
#pragma unroll
  for (int m = 0; m < 2; ++m)
#pragma unroll
    for (int dt = 0; dt < 8; ++dt) o[m][dt] = (f32x4){0.f, 0.f, 0.f, 0.f};
  float mrun[2] = {-3e38f, -3e38f}, lrun[2] = {0.f, 0.f};   // lrun: per-lane partial

  const int kb0 = sp * 16;   // 16 k-tiles per split (64 total / 4)

  // per-lane staging src pointers (advance by constants each k-tile)
  const f16* kp[4];
  const f16* vp[4];
#pragma unroll
  for (int c4 = 0; c4 < 4; ++c4) {
    int c = w * 4 + c4;
    int row = c * 4 + (lane >> 4);
    int fk = (row & 3) | ((row & 8) >> 1);
    kp[c4] = Kh + (size_t)h * N_TOK * DH + (size_t)(kb0 * 64 + row) * DH + ((lane & 15) ^ fk) * 8;
    int rowv = c * 8 + (lane >> 3);
    vp[c4] = Vt + (size_t)h * DH * N_TOK + (size_t)rowv * N_TOK + kb0 * 64 + ((lane & 7) ^ (rowv & 7)) * 8;
  }

  const char* kd = smem;
  const char* vd = smem + 16384;

  for (int it = 0; it < 16; ++it) {
    // stage current tile; pointers advance for next
#pragma unroll
    for (int c4 = 0; c4 < 4; ++c4) {
      int c = w * 4 + c4;
      GLD16(kp[c4], (char*)smem + c * 1024);
      GLD16(vp[c4], (char*)smem + 16384 + c * 1024);
      kp[c4] += 64 * DH;    // next k-tile: +64 K-rows
      vp[c4] += 64;         // next k-tile: +64 tokens within d-row
    }
    __syncthreads();               // stage writes landed (vmcnt(0) + barrier)

    f32x4 sv[2][4];
    __builtin_amdgcn_s_setprio(1);
#pragma unroll
    for (int nt = 0; nt < 4; ++nt) {
      f32x4 a0 = {0.f, 0.f, 0.f, 0.f}, a1 = {0.f, 0.f, 0.f, 0.f};
#pragma unroll
      for (int kt = 0; kt < 4; ++kt) {
        f16x8 kf = *(const f16x8*)(kd + koff[nt][kt]);
        a0 = __builtin_amdgcn_mfma_f32_16x16x32_f16(kf, qf[0][kt], a0, 0, 0, 0);
        a1 = __builtin_amdgcn_mfma_f32_16x16x32_f16(kf, qf[1][kt], a1, 0, 0, 0);
      }
      sv[0][nt] = a0; sv[1][nt] = a1;
    }
    __builtin_amdgcn_s_setprio(0);

    f16x8 pf[2][2];
#pragma unroll
    for (int m = 0; m < 2; ++m) {
      f32x4 mv;
#pragma unroll
      for (int r = 0; r < 4; ++r)
        mv[r] = fmaxf(fmaxf(sv[m][0][r], sv[m][1][r]), fmaxf(sv[m][2][r], sv[m][3][r]));
      float pmax = fmaxf(fmaxf(mv[0], mv[1]), fmaxf(mv[2], mv[3]));
      // defer-max, shfl-free common path: lane-local threshold check (log2 units)
      if (!__all(pmax - mrun[m] <= 8.f)) {
        float rm = fmaxf(pmax, __shfl_xor(pmax, 16));
        rm = fmaxf(rm, __shfl_xor(rm, 32));
        float mnew = fmaxf(mrun[m], rm);
        float sc = EXP2F(mrun[m] - mnew);
        lrun[m] *= sc;
#pragma unroll
        for (int dt = 0; dt < 8; ++dt) o[m][dt] *= sc;
        mrun[m] = mnew;
      }
      float mr = mrun[m];
      f32x4 ps = {0.f, 0.f, 0.f, 0.f};
#pragma unroll
      for (int nt = 0; nt < 4; ++nt)
#pragma unroll
        for (int r = 0; r < 4; ++r) {
          float p = EXP2F(sv[m][nt][r] - mr);
          sv[m][nt][r] = p;
          ps[r] += p;
        }
      lrun[m] += (ps[0] + ps[1]) + (ps[2] + ps[3]);   // per-lane partial sum
#pragma unroll
      for (int ks = 0; ks < 2; ++ks) {
        union { f16x8 v; hf2 hh[4]; } u;
        u.hh[0] = __builtin_amdgcn_cvt_pkrtz(sv[m][2 * ks][0], sv[m][2 * ks][1]);
        u.hh[1] = __builtin_amdgcn_cvt_pkrtz(sv[m][2 * ks][2], sv[m][2 * ks][3]);
        u.hh[2] = __builtin_amdgcn_cvt_pkrtz(sv[m][2 * ks + 1][0], sv[m][2 * ks + 1][1]);
        u.hh[3] = __builtin_amdgcn_cvt_pkrtz(sv[m][2 * ks + 1][2], sv[m][2 * ks + 1][3]);
        pf[m][ks] = u.v;
      }
    }

    __builtin_amdgcn_s_setprio(1);
#pragma unroll
    for (int ks = 0; ks < 2; ++ks)
#pragma unroll
      for (int dt = 0; dt < 8; ++dt) {
        f16x8 vf = *(const f16x8*)(vd + voff[ks][dt]);
        o[0][dt] = __builtin_amdgcn_mfma_f32_16x16x32_f16(vf, pf[0][ks], o[0][dt], 0, 0, 0);
        o[1][dt] = __builtin_amdgcn_mfma_f32_16x16x32_f16(vf, pf[1][ks], o[1][dt], 0, 0, 0);
      }
    __builtin_amdgcn_s_setprio(0);

    __syncthreads();               // all reads done before next stage overwrites
  }

  // epilogue: l-normalized O stored [128 n][128 d], packed 8B stores
  f16* ob = opart + ((size_t)((sp * 8 + h) * 32 + qb)) * 16384;
  float* mlb = mlpart + ((size_t)((sp * 8 + h) * 32 + qb)) * 256;
#pragma unroll
  for (int m = 0; m < 2; ++m) {
    float lr = lrun[m];
    lr += __shfl_xor(lr, 16);
    lr += __shfl_xor(lr, 32);
    float rl = 1.0f / lr;
    int n = w * 32 + m * 16 + l16;
#pragma unroll
    for (int dt = 0; dt < 8; ++dt) {
      union { hf4 v; hf2 h[2]; } u;
      u.h[0] = __builtin_amdgcn_cvt_pkrtz(o[m][dt][0] * rl, o[m][dt][1] * rl);
      u.h[1] = __builtin_amdgcn_cvt_pkrtz(o[m][dt][2] * rl, o[m][dt][3] * rl);
      *(hf4*)(ob + (size_t)n * 128 + dt * 16 + 4 * lhi) = u.v;
    }
    if (lhi == 0) {
      mlb[n] = mrun[m];
      mlb[128 + n] = lr;
    }
  }
}

// ---------------- proj GEMM with fused 4-way split-K combine -------------
// A-build vectorized (f16x8); GEMM waves split over OUTPUT dt over full K.
__global__ __launch_bounds__(256) void proj_combine(
    const f16* __restrict__ opart, const float* __restrict__ mlpart,
    const f16* __restrict__ wpT, const float* __restrict__ b_proj,
    float* __restrict__ out)
{
  const int tid = threadIdx.x;
  const int w = tid >> 6;
  const int lane = tid & 63;
  const int l16 = lane & 15, lhi = lane >> 4;
  const int rb = blockIdx.x * 16;
  const int qb = rb >> 7;            // opart tile (128 rows)
  const int nl0 = rb & 127;          // n offset within tile

  __shared__ f16 A[16][1032];        // [n][k = h*128+d], +8 pad
  __shared__ float wl[8][16][4];     // per (h, n): c_i = n_i * rl, i = 0..3

  const float isc = 0.08838834764831845f;  // 1/sqrt(128)
  if (tid < 128) {
    int hh = tid >> 4, n = tid & 15;
    float mi[4], li[4];
#pragma unroll
    for (int i = 0; i < 4; ++i) {
      const float* ml = mlpart + ((size_t)((i * 8 + hh) * 32 + qb)) * 256 + nl0 + n;
      mi[i] = ml[0]; li[i] = ml[128];
    }
    float mt = fmaxf(fmaxf(mi[0], mi[1]), fmaxf(mi[2], mi[3]));
    float ni[4], tot = 0.f;
#pragma unroll
    for (int i = 0; i < 4; ++i) { ni[i] = EXP2F(mi[i] - mt) * li[i]; tot += ni[i]; }
    float rl = isc / tot;
#pragma unroll
    for (int i = 0; i < 4; ++i) wl[hh][n][i] = ni[i] * rl;
  }
  __syncthreads();

  {
    int n = tid & 15, c = tid >> 4;          // c = 0..15 -> 64-k chunk
    int hh = c >> 1, d0 = (c & 1) * 64;
    size_t roff = (size_t)(nl0 + n) * 128 + d0;
    const f16* O0 = opart + ((size_t)((0 + hh) * 32 + qb)) * 16384 + roff;
    const f16* O1 = opart + ((size_t)((8 + hh) * 32 + qb)) * 16384 + roff;
    const f16* O2 = opart + ((size_t)((16 + hh) * 32 + qb)) * 16384 + roff;
    const f16* O3 = opart + ((size_t)((24 + hh) * 32 + qb)) * 16384 + roff;
    float w0 = wl[hh][n][0], w1 = wl[hh][n][1], w2 = wl[hh][n][2], w3 = wl[hh][n][3];
#pragma unroll
    for (int j = 0; j < 8; ++j) {
      f16x8 a0 = *(const f16x8*)(O0 + j * 8);
      f16x8 a1 = *(const f16x8*)(O1 + j * 8);
      f16x8 a2 = *(const f16x8*)(O2 + j * 8);
      f16x8 a3 = *(const f16x8*)(O3 + j * 8);
      f16x8 res;
#pragma unroll
      for (int e = 0; e < 8; ++e)
        res[e] = (f16)((float)a0[e] * w0 + (float)a1[e] * w1
                     + (float)a2[e] * w2 + (float)a3[e] * w3);
      *(f16x8*)(&A[n][hh * 128 + d0 + j * 8]) = res;
    }
  }
  __syncthreads();

  f32x4 o[2];
  o[0] = (f32x4){0.f, 0.f, 0.f, 0.f};
  o[1] = (f32x4){0.f, 0.f, 0.f, 0.f};

#pragma unroll
  for (int kb = 0; kb < 32; ++kb) {
    int k0 = kb * 32 + lhi * 8;
    f16x8 a = *(const f16x8*)(&A[l16][k0]);
#pragma unroll
    for (int dtl = 0; dtl < 2; ++dtl) {
      int dt = w * 2 + dtl;
      f16x8 b = *(const f16x8*)(wpT + (size_t)(dt * 16 + l16) * 1024 + k0);
      o[dtl] = __builtin_amdgcn_mfma_f32_16x16x32_f16(a, b, o[dtl], 0, 0, 0);
    }
  }

#pragma unroll
  for (int dtl = 0; dtl < 2; ++dtl) {
    int col = (w * 2 + dtl) * 16 + l16;
    float bp = b_proj[col];
#pragma unroll
    for (int r = 0; r < 4; ++r)
      out[(size_t)(rb + lhi * 4 + r) * 128 + col] = o[dtl][r] + bp;
  }
}

// ---------------- launch --------------------------------------------------
extern "C" void kernel_launch(void* const* d_in, const int* in_sizes, int n_in,
                              void* d_out, int out_size, void* d_ws, size_t ws_size,
                              hipStream_t stream) {
  const float* x      = (const float*)d_in[0];
  const float* w_qkv  = (const float*)d_in[1];
  const float* b_qkv  = (const float*)d_in[2];
  const float* w_proj = (const float*)d_in[3];
  const float* b_proj = (const float*)d_in[4];
  float* out = (float*)d_out;

  char* ws = (char*)d_ws;
  const size_t MB = 1024 * 1024;
  f16*   Qh     = (f16*)(ws);                    // 8 MiB  [h][n][d]
  f16*   Kh     = (f16*)(ws + 8 * MB);           // 8 MiB  [h][n][d]
  f16*   Vt     = (f16*)(ws + 16 * MB);          // 8 MiB  [h][d][n]
  f16*   opart  = (f16*)(ws + 24 * MB);          // 32 MiB [sp4][h][qb32][n128][d128]
  float* mlpart = (float*)(ws + 56 * MB);        // 1 MiB
  f16*   wpT    = (f16*)(ws + 57 * MB);                       // 0.25 MiB
  f16*   wqkvT  = (f16*)(ws + 57 * MB + 256 * 1024);          // 0.75 MiB
  float* bperm  = (float*)(ws + 58 * MB);                     // 12 KiB

  hipLaunchKernelGGL(conv_weights, dim3(2048), dim3(256), 0, stream,
                     w_proj, w_qkv, b_qkv, wpT, wqkvT, bperm);
  hipLaunchKernelGGL(qkv_gemm2, dim3(24, 32), dim3(256), 0, stream,
                     x, wqkvT, bperm, Qh, Kh, Vt);
  hipLaunchKernelGGL(flash_attn, dim3(1024), dim3(256), 0, stream,
                     Qh, Kh, Vt, opart, mlpart);
  hipLaunchKernelGGL(proj_combine, dim3(256), dim3(256), 0, stream,
                     opart, mlpart, wpT, b_proj, out);
}

// Round 23
// 122.224 us; speedup vs baseline: 2.3869x; 2.3869x over previous
//
#include <hip/hip_runtime.h>
#include <hip/hip_fp16.h>

// MultiHeadAttention: n=4096, e=128, H=8, fp32 in/out.
// [conv_weights] w_proj -> f16^T; w_qkv -> f16 permuted-transposed (Q pre-scaled
//                by log2(e)); x -> f16 copy
// [qkv_gemm2]    f16 MFMA GEMM; V d-major direct, Q/K n-major via LDS transpose
// [flash_attn]   R20 structure: KVBLK=128, 64KB single-buf K+V, 2 blocks/CU,
//                split-K x2, two 64-key halves per staged tile. Full 4-bit XOR
//                swizzle keys (K: fk4(row); V: rowv&15). Half-1 V slot composed
//                by XOR 128 (R22 lesson: (s+8)^fk != (s^fk)+8 when fk>=8 -- the
//                additive form read past the tile -> NaN). K half-1 = +16384
//                (row bit 6 not in fk4 -> plain add valid).
// [proj_combine] 2-way combine + dt-split GEMM (no LDS reduction phase)

#define N_TOK 4096
#define DH 128
#define NH 8

#define EXP2F(x) __builtin_amdgcn_exp2f(x)

typedef _Float16 f16;
typedef __attribute__((ext_vector_type(8))) _Float16 f16x8;
typedef __attribute__((ext_vector_type(2))) __fp16 hf2;
typedef __attribute__((ext_vector_type(4))) __fp16 hf4;
typedef __attribute__((ext_vector_type(4))) float f32x4;

#define GLD16(gsrc, ldst) __builtin_amdgcn_global_load_lds( \
    (const __attribute__((address_space(1))) void*)(gsrc), \
    (__attribute__((address_space(3))) void*)(ldst), 16, 0, 0)

// 4-bit swizzle key for K rows (bijective within a 16-chunk 256B row)
__device__ __forceinline__ int fk4(int row) {
  return (row & 3) | ((row & 8) >> 1) | ((row & 16) >> 1);
}

// ---------------- conv: weights + x, one launch ---------------------------
__global__ __launch_bounds__(256) void conv_weights(
    const float* __restrict__ w_proj, const float* __restrict__ w_qkv,
    const float* __restrict__ b_qkv, const float* __restrict__ x,
    f16* __restrict__ wpT, f16* __restrict__ wqkvT, float* __restrict__ bperm,
    f16* __restrict__ xh)
{
  int t = blockIdx.x * 256 + threadIdx.x;   // 0 .. 1048575
  if (t < 131072) {
    int k = t >> 7, col = t & 127;
    wpT[col * 1024 + k] = (f16)w_proj[t];
  } else if (t < 524288) {
    t -= 131072;                            // 0 .. 393215 = 128 * 3072
    int k = t / 3072;
    int col = t - k * 3072;
    int hh = col / 384;
    int rem = col - hh * 384;
    int d = rem / 3;
    int s = rem - d * 3;
    int colp = s * 1024 + hh * 128 + d;
    float scale = (s == 0) ? 1.4426950408889634f : 1.0f;
    wqkvT[colp * 128 + k] = (f16)(w_qkv[t] * scale);
    if (k == 0) bperm[colp] = b_qkv[col] * scale;
  } else {
    t -= 524288;                            // 0 .. 524287 = 4096*128
    xh[t] = (f16)x[t];
  }
}

// ---------------- qkv GEMM v2: f16 MFMA --------------------------------
__global__ __launch_bounds__(256) void qkv_gemm2(
    const f16* __restrict__ xh, const f16* __restrict__ wqkvT,
    const float* __restrict__ bperm,
    f16* __restrict__ Qh, f16* __restrict__ Kh, f16* __restrict__ Vt)
{
  const int cb = blockIdx.x;               // 0..23: s = cb>>3, h = cb&7
  const int rb = blockIdx.y;               // 0..31: rows rb*128
  const int tid = threadIdx.x;
  const int w = tid >> 6, lane = tid & 63;
  const int l16 = lane & 15, lhi = lane >> 4;
  const int s = cb >> 3, h = cb & 7;

  f16x8 xf[2][4];
#pragma unroll
  for (int m = 0; m < 2; ++m)
#pragma unroll
    for (int kt = 0; kt < 4; ++kt)
      xf[m][kt] = *(const f16x8*)(xh +
          (size_t)(rb * 128 + w * 32 + m * 16 + l16) * 128 + kt * 32 + lhi * 8);

  f32x4 acc[8][2];
#pragma unroll
  for (int nt = 0; nt < 8; ++nt)
#pragma unroll
    for (int m = 0; m < 2; ++m) acc[nt][m] = (f32x4){0.f, 0.f, 0.f, 0.f};

#pragma unroll
  for (int nt = 0; nt < 8; ++nt)
#pragma unroll
    for (int kt = 0; kt < 4; ++kt) {
      f16x8 wf = *(const f16x8*)(wqkvT + (size_t)(cb * 128 + nt * 16 + l16) * 128 + kt * 32 + lhi * 8);
      acc[nt][0] = __builtin_amdgcn_mfma_f32_16x16x32_f16(wf, xf[0][kt], acc[nt][0], 0, 0, 0);
      acc[nt][1] = __builtin_amdgcn_mfma_f32_16x16x32_f16(wf, xf[1][kt], acc[nt][1], 0, 0, 0);
    }

#pragma unroll
  for (int nt = 0; nt < 8; ++nt) {
    f32x4 bb = *(const f32x4*)(bperm + cb * 128 + nt * 16 + 4 * lhi);
#pragma unroll
    for (int m = 0; m < 2; ++m) acc[nt][m] += bb;
  }

  if (s == 2) {            // V: direct d-major store [h*128+d][n]
#pragma unroll
    for (int nt = 0; nt < 8; ++nt)
#pragma unroll
      for (int m = 0; m < 2; ++m)
#pragma unroll
        for (int r = 0; r < 4; ++r)
          Vt[(size_t)(h * 128 + nt * 16 + 4 * lhi + r) * N_TOK + rb * 128 + w * 32 + m * 16 + l16] =
              (f16)acc[nt][m][r];
  } else {                 // Q/K: LDS transpose -> n-major [n][d]
    __shared__ f16 tr[128][136];
#pragma unroll
    for (int nt = 0; nt < 8; ++nt)
#pragma unroll
      for (int m = 0; m < 2; ++m)
#pragma unroll
        for (int r = 0; r < 4; ++r)
          tr[w * 32 + m * 16 + l16][nt * 16 + 4 * lhi + r] = (f16)acc[nt][m][r];
    __syncthreads();
    f16* dst = (s == 0 ? Qh : Kh) + (size_t)(h * N_TOK + rb * 128) * 128;
    int r = tid >> 1, dh = (tid & 1) * 64;
#pragma unroll
    for (int i = 0; i < 8; ++i)
      *(f16x8*)(dst + r * 128 + dh + i * 8) = *(const f16x8*)(&tr[r][dh + i * 8]);
  }
}

// ---------------- flash attention: KVBLK=128, 64 KB LDS, split-K x2 ------
// grid 512: h = bid&7 (XCD pin), sp = (bid>>3)&1, qb = bid>>4 (0..31).
// Block covers 128 q-rows. K tile [128 kr][128 d] @0; V tile [128 d][128 n] @32K.
__global__ __launch_bounds__(256, 2) void flash_attn(
    const f16* __restrict__ Qh, const f16* __restrict__ Kh,
    const f16* __restrict__ Vt, f16* __restrict__ opart, float* __restrict__ mlpart)
{
  const int bid = blockIdx.x;
  const int h = bid & 7, sp = (bid >> 3) & 1, qb = bid >> 4;
  const int tid = threadIdx.x;
  const int w = tid >> 6, lane = tid & 63;
  const int l16 = lane & 15, lhi = lane >> 4;

  __shared__ __align__(16) char smem[65536];   // K @0 (32K), V @32K (32K)

  f16x8 qf[2][4];
#pragma unroll
  for (int m = 0; m < 2; ++m)
#pragma unroll
    for (int kt = 0; kt < 4; ++kt)
      qf[m][kt] = *(const f16x8*)(Qh +
          (size_t)(h * N_TOK + qb * 128 + w * 32 + m * 16 + l16) * DH + kt * 32 + lhi * 8);

  // K A-row permutation pi (rows 0..63); half-1 = +64 rows = +16384 bytes
  // (row+64 flips bit 6 only -> fk4 unchanged -> additive).
  int koff[4][4], voff[2][8];
#pragma unroll
  for (int nt = 0; nt < 4; ++nt) {
    int row = 32 * (nt >> 1) + 8 * (l16 >> 2) + 4 * (nt & 1) + (l16 & 3);
    int fk = fk4(row);
#pragma unroll
    for (int kt = 0; kt < 4; ++kt)
      koff[nt][kt] = row * 256 + ((kt * 4 + lhi) ^ fk) * 16;
  }
#pragma unroll
  for (int ks = 0; ks < 2; ++ks)
#pragma unroll
    for (int dt = 0; dt < 8; ++dt) {
      int rowv = dt * 16 + l16;
      int fk = rowv & 15;          // full 4-bit key for V (= l16)
      voff[ks][dt] = rowv * 256 + (((ks * 4 + lhi) ^ fk)) * 16;
    }

  f32x4 o[2][8];
#pragma unroll
  for (int m = 0; m < 2; ++m)
#pragma unroll
    for (int dt = 0; dt < 8; ++dt) o[m][dt] = (f32x4){0.f, 0.f, 0.f, 0.f};
  float mrun[2] = {-3e38f, -3e38f}, lrun[2] = {0.f, 0.f};

  const f16* Kgh = Kh + (size_t)h * N_TOK * DH;
  const f16* Vgh = Vt + (size_t)h * DH * N_TOK;

  // wave w stages K rows (c=w*8+c8)*4.. and V rows likewise; 16 GLD16/wave.
  auto stage = [&](int kb) {
#pragma unroll
    for (int c8 = 0; c8 < 8; ++c8) {
      int c = w * 8 + c8;   // 0..31
      int row = c * 4 + (lane >> 4);
      {
        int chunk = (lane & 15) ^ fk4(row);
        const f16* src = Kgh + (size_t)(kb * 128 + row) * DH + chunk * 8;
        GLD16(src, (char*)smem + c * 1024);
      }
      {
        int chunk = (lane & 15) ^ (row & 15);
        const f16* src = Vgh + (size_t)row * N_TOK + kb * 128 + chunk * 8;
        GLD16(src, (char*)smem + 32768 + c * 1024);
      }
    }
  };

  const char* kd = smem;
  const char* vd = smem + 32768;
  const int kb0 = sp * 16;

  for (int kb = kb0; kb < kb0 + 16; ++kb) {
    stage(kb);
    __syncthreads();               // stage writes landed (vmcnt(0) + barrier)

#pragma unroll
    for (int half = 0; half < 2; ++half) {
      const int kadd = half * 16384;   // +64 K-rows (bit 6; fk4 invariant)
      const int vxor = half * 128;     // slot bit 3 <-> byte bit 7: XOR compose
                                       // ((s+8)^fk)*16 == ((s^fk)*16) ^ 128 (s<8)

      f32x4 sv[2][4];
      __builtin_amdgcn_s_setprio(1);
#pragma unroll
      for (int nt = 0; nt < 4; ++nt) {
        f32x4 a0 = {0.f, 0.f, 0.f, 0.f}, a1 = {0.f, 0.f, 0.f, 0.f};
#pragma unroll
        for (int kt = 0; kt < 4; ++kt) {
          f16x8 kf = *(const f16x8*)(kd + kadd + koff[nt][kt]);
          a0 = __builtin_amdgcn_mfma_f32_16x16x32_f16(kf, qf[0][kt], a0, 0, 0, 0);
          a1 = __builtin_amdgcn_mfma_f32_16x16x32_f16(kf, qf[1][kt], a1, 0, 0, 0);
        }
        sv[0][nt] = a0; sv[1][nt] = a1;
      }
      __builtin_amdgcn_s_setprio(0);

      f16x8 pf[2][2];
#pragma unroll
      for (int m = 0; m < 2; ++m) {
        f32x4 mv;
#pragma unroll
        for (int r = 0; r < 4; ++r)
          mv[r] = fmaxf(fmaxf(sv[m][0][r], sv[m][1][r]), fmaxf(sv[m][2][r], sv[m][3][r]));
        float pmax = fmaxf(fmaxf(mv[0], mv[1]), fmaxf(mv[2], mv[3]));
        // defer-max, shfl-free common path (log2 units)
        if (!__all(pmax - mrun[m] <= 8.f)) {
          float rm = fmaxf(pmax, __shfl_xor(pmax, 16));
          rm = fmaxf(rm, __shfl_xor(rm, 32));
          float mnew = fmaxf(mrun[m], rm);
          float sc = EXP2F(mrun[m] - mnew);
          lrun[m] *= sc;
#pragma unroll
          for (int dt = 0; dt < 8; ++dt) o[m][dt] *= sc;
          mrun[m] = mnew;
        }
        float mr = mrun[m];
        f32x4 ps = {0.f, 0.f, 0.f, 0.f};
#pragma unroll
        for (int nt = 0; nt < 4; ++nt)
#pragma unroll
          for (int r = 0; r < 4; ++r) {
            float p = EXP2F(sv[m][nt][r] - mr);
            sv[m][nt][r] = p;
            ps[r] += p;
          }
        lrun[m] += (ps[0] + ps[1]) + (ps[2] + ps[3]);
#pragma unroll
        for (int ks = 0; ks < 2; ++ks) {
          union { f16x8 v; hf2 hh[4]; } u;
          u.hh[0] = __builtin_amdgcn_cvt_pkrtz(sv[m][2 * ks][0], sv[m][2 * ks][1]);
          u.hh[1] = __builtin_amdgcn_cvt_pkrtz(sv[m][2 * ks][2], sv[m][2 * ks][3]);
          u.hh[2] = __builtin_amdgcn_cvt_pkrtz(sv[m][2 * ks + 1][0], sv[m][2 * ks + 1][1]);
          u.hh[3] = __builtin_amdgcn_cvt_pkrtz(sv[m][2 * ks + 1][2], sv[m][2 * ks + 1][3]);
          pf[m][ks] = u.v;
        }
      }

      __builtin_amdgcn_s_setprio(1);
#pragma unroll
      for (int ks = 0; ks < 2; ++ks)
#pragma unroll
        for (int dt = 0; dt < 8; ++dt) {
          f16x8 vf = *(const f16x8*)(vd + (voff[ks][dt] ^ vxor));
          o[0][dt] = __builtin_amdgcn_mfma_f32_16x16x32_f16(vf, pf[0][ks], o[0][dt], 0, 0, 0);
          o[1][dt] = __builtin_amdgcn_mfma_f32_16x16x32_f16(vf, pf[1][ks], o[1][dt], 0, 0, 0);
        }
      __builtin_amdgcn_s_setprio(0);
    }

    __syncthreads();               // all reads done before next stage overwrites
  }

  // epilogue: l-normalized O stored [128 n][128 d], packed 8B stores
  f16* ob = opart + ((size_t)((sp * 8 + h) * 32 + qb)) * 16384;
  float* mlb = mlpart + ((size_t)((sp * 8 + h) * 32 + qb)) * 256;
#pragma unroll
  for (int m = 0; m < 2; ++m) {
    float lr = lrun[m];
    lr += __shfl_xor(lr, 16);
    lr += __shfl_xor(lr, 32);
    float rl = 1.0f / lr;
    int n = w * 32 + m * 16 + l16;
#pragma unroll
    for (int dt = 0; dt < 8; ++dt) {
      union { hf4 v; hf2 h[2]; } u;
      u.h[0] = __builtin_amdgcn_cvt_pkrtz(o[m][dt][0] * rl, o[m][dt][1] * rl);
      u.h[1] = __builtin_amdgcn_cvt_pkrtz(o[m][dt][2] * rl, o[m][dt][3] * rl);
      *(hf4*)(ob + (size_t)n * 128 + dt * 16 + 4 * lhi) = u.v;
    }
    if (lhi == 0) {
      mlb[n] = mrun[m];
      mlb[128 + n] = lr;
    }
  }
}

// ---------------- proj GEMM with fused 2-way split-K combine -------------
// A-build vectorized (f16x8); GEMM waves split over OUTPUT dt over full K.
__global__ __launch_bounds__(256) void proj_combine(
    const f16* __restrict__ opart, const float* __restrict__ mlpart,
    const f16* __restrict__ wpT, const float* __restrict__ b_proj,
    float* __restrict__ out)
{
  const int tid = threadIdx.x;
  const int w = tid >> 6;
  const int lane = tid & 63;
  const int l16 = lane & 15, lhi = lane >> 4;
  const int rb = blockIdx.x * 16;
  const int qb = rb >> 7;            // opart tile (128 rows)
  const int nl0 = rb & 127;          // n offset within tile

  __shared__ f16 A[16][1032];        // [n][k = h*128+d], +8 pad
  __shared__ float wl[8][16][2];     // per (h, n): c0, c1 (already * isc/tot)

  const float isc = 0.08838834764831845f;  // 1/sqrt(128)
  if (tid < 128) {
    int hh = tid >> 4, n = tid & 15;
    const float* ml0 = mlpart + ((size_t)((0 + hh) * 32 + qb)) * 256 + nl0 + n;
    const float* ml1 = mlpart + ((size_t)((8 + hh) * 32 + qb)) * 256 + nl0 + n;
    float m0 = ml0[0], l0 = ml0[128], m1 = ml1[0], l1 = ml1[128];
    float mt = fmaxf(m0, m1);
    float n0 = EXP2F(m0 - mt) * l0, n1 = EXP2F(m1 - mt) * l1;
    float rl = isc / (n0 + n1);
    wl[hh][n][0] = n0 * rl;
    wl[hh][n][1] = n1 * rl;
  }
  __syncthreads();

  {
    int n = tid & 15, c = tid >> 4;          // c = 0..15 -> 64-k chunk
    int hh = c >> 1, d0 = (c & 1) * 64;
    size_t roff = (size_t)(nl0 + n) * 128 + d0;
    const f16* O0 = opart + ((size_t)((0 + hh) * 32 + qb)) * 16384 + roff;
    const f16* O1 = opart + ((size_t)((8 + hh) * 32 + qb)) * 16384 + roff;
    float w0 = wl[hh][n][0], w1 = wl[hh][n][1];
#pragma unroll
    for (int j = 0; j < 8; ++j) {
      f16x8 a0 = *(const f16x8*)(O0 + j * 8);
      f16x8 a1 = *(const f16x8*)(O1 + j * 8);
      f16x8 res;
#pragma unroll
      for (int e = 0; e < 8; ++e)
        res[e] = (f16)((float)a0[e] * w0 + (float)a1[e] * w1);
      *(f16x8*)(&A[n][hh * 128 + d0 + j * 8]) = res;
    }
  }
  __syncthreads();

  f32x4 o[2];
  o[0] = (f32x4){0.f, 0.f, 0.f, 0.f};
  o[1] = (f32x4){0.f, 0.f, 0.f, 0.f};

#pragma unroll
  for (int kb = 0; kb < 32; ++kb) {
    int k0 = kb * 32 + lhi * 8;
    f16x8 a = *(const f16x8*)(&A[l16][k0]);
#pragma unroll
    for (int dtl = 0; dtl < 2; ++dtl) {
      int dt = w * 2 + dtl;
      f16x8 b = *(const f16x8*)(wpT + (size_t)(dt * 16 + l16) * 1024 + k0);
      o[dtl] = __builtin_amdgcn_mfma_f32_16x16x32_f16(a, b, o[dtl], 0, 0, 0);
    }
  }

#pragma unroll
  for (int dtl = 0; dtl < 2; ++dtl) {
    int col = (w * 2 + dtl) * 16 + l16;
    float bp = b_proj[col];
#pragma unroll
    for (int r = 0; r < 4; ++r)
      out[(size_t)(rb + lhi * 4 + r) * 128 + col] = o[dtl][r] + bp;
  }
}

// ---------------- launch --------------------------------------------------
extern "C" void kernel_launch(void* const* d_in, const int* in_sizes, int n_in,
                              void* d_out, int out_size, void* d_ws, size_t ws_size,
                              hipStream_t stream) {
  const float* x      = (const float*)d_in[0];
  const float* w_qkv  = (const float*)d_in[1];
  const float* b_qkv  = (const float*)d_in[2];
  const float* w_proj = (const float*)d_in[3];
  const float* b_proj = (const float*)d_in[4];
  float* out = (float*)d_out;

  char* ws = (char*)d_ws;
  const size_t MB = 1024 * 1024;
  f16*   Qh     = (f16*)(ws);                    // 8 MiB  [h][n][d]
  f16*   Kh     = (f16*)(ws + 8 * MB);           // 8 MiB  [h][n][d]
  f16*   Vt     = (f16*)(ws + 16 * MB);          // 8 MiB  [h][d][n]
  f16*   opart  = (f16*)(ws + 24 * MB);          // 16 MiB [sp2][h][qb32][n128][d128]
  float* mlpart = (float*)(ws + 40 * MB);        // 0.5 MiB
  f16*   wpT    = (f16*)(ws + 40 * MB + 512 * 1024);          // 0.25 MiB
  f16*   wqkvT  = (f16*)(ws + 40 * MB + 768 * 1024);          // 0.75 MiB
  float* bperm  = (float*)(ws + 41 * MB + 512 * 1024);        // 12 KiB
  f16*   xh     = (f16*)(ws + 41 * MB + 768 * 1024);          // 1 MiB

  hipLaunchKernelGGL(conv_weights, dim3(4096), dim3(256), 0, stream,
                     w_proj, w_qkv, b_qkv, x, wpT, wqkvT, bperm, xh);
  hipLaunchKernelGGL(qkv_gemm2, dim3(24, 32), dim3(256), 0, stream,
                     xh, wqkvT, bperm, Qh, Kh, Vt);
  hipLaunchKernelGGL(flash_attn, dim3(512), dim3(256), 0, stream,
                     Qh, Kh, Vt, opart, mlpart);
  hipLaunchKernelGGL(proj_combine, dim3(256), dim3(256), 0, stream,
                     opart, mlpart, wpT, b_proj, out);
}